// Round 1
// baseline (5334.332 us; speedup 1.0000x reference)
//
#include <hip/hip_runtime.h>

#define N_NODES 50000
#define N_EDGES 800000
#define DIM 96

// ---------------------------------------------------------------------------
// Kernel 1: scatter-add edge_attr rows into agg[dst]. One thread per
// (edge, float4-chunk): 24 chunks of 4 floats per 96-wide row.
// fp32 atomicAdd is device-scope by default (guide §6 G12).
// ---------------------------------------------------------------------------
__global__ __launch_bounds__(256) void scatter_kernel(
    const float* __restrict__ edge_attr, const int* __restrict__ ei,
    float* __restrict__ agg) {
  int tid = blockIdx.x * 256 + threadIdx.x;
  if (tid >= N_EDGES * 24) return;
  int e = tid / 24;
  int c = tid - e * 24;
  int d = ei[N_EDGES + e];  // edge_index[1][e] = destination
  const float4 v =
      *reinterpret_cast<const float4*>(edge_attr + (size_t)e * DIM + c * 4);
  float* p = agg + (size_t)d * DIM + c * 4;
  atomicAdd(p + 0, v.x);
  atomicAdd(p + 1, v.y);
  atomicAdd(p + 2, v.z);
  atomicAdd(p + 3, v.w);
}

// ---------------------------------------------------------------------------
// Kernel 2: copy edge_index into the output buffer as float values
// (harness reads the concatenated tuple as one float32 buffer; indices
// < 50000 are exactly representable).
// ---------------------------------------------------------------------------
__global__ __launch_bounds__(256) void copy_ei_kernel(
    const int* __restrict__ ei, float* __restrict__ out) {
  int tid = blockIdx.x * 256 + threadIdx.x;
  if (tid < 2 * N_EDGES) out[tid] = (float)ei[tid];
}

// ---------------------------------------------------------------------------
// Kernel 3: node MLP. 192 threads = 2 sub-groups of 96; each sub handles one
// node row. Input row (x||agg, 192 floats) staged in LDS, broadcast-read;
// weight rows W[k*96+j] read coalesced across j (L1/L2-resident).
// ---------------------------------------------------------------------------
__global__ __launch_bounds__(192) void node_mlp_kernel(
    const float* __restrict__ x, const float* __restrict__ agg,
    const float* __restrict__ W1, const float* __restrict__ b1,
    const float* __restrict__ W2, const float* __restrict__ b2,
    float* __restrict__ out) {
  __shared__ float s_in[2][192];
  __shared__ float s_h[2][96];
  const int sub = threadIdx.x / 96;
  const int j = threadIdx.x - sub * 96;
  const int node = blockIdx.x * 2 + sub;

  s_in[sub][j] = x[(size_t)node * DIM + j];
  s_in[sub][96 + j] = agg[(size_t)node * DIM + j];
  __syncthreads();

  float acc = b1[j];
  for (int k = 0; k < 192; k += 4) {
    const float4 iv = *reinterpret_cast<const float4*>(&s_in[sub][k]);
    acc = fmaf(iv.x, W1[(k + 0) * DIM + j], acc);
    acc = fmaf(iv.y, W1[(k + 1) * DIM + j], acc);
    acc = fmaf(iv.z, W1[(k + 2) * DIM + j], acc);
    acc = fmaf(iv.w, W1[(k + 3) * DIM + j], acc);
  }
  s_h[sub][j] = fmaxf(acc, 0.0f);
  __syncthreads();

  float acc2 = b2[j];
  for (int k = 0; k < 96; k += 4) {
    const float4 hv = *reinterpret_cast<const float4*>(&s_h[sub][k]);
    acc2 = fmaf(hv.x, W2[(k + 0) * DIM + j], acc2);
    acc2 = fmaf(hv.y, W2[(k + 1) * DIM + j], acc2);
    acc2 = fmaf(hv.z, W2[(k + 2) * DIM + j], acc2);
    acc2 = fmaf(hv.w, W2[(k + 3) * DIM + j], acc2);
  }
  out[(size_t)node * DIM + j] = acc2;
}

// ---------------------------------------------------------------------------
// Kernel 4: edge MLP. Same scheme; input row = x[src] || x[dst] || edge_attr
// (288 floats) gathered into LDS.
// ---------------------------------------------------------------------------
__global__ __launch_bounds__(192) void edge_mlp_kernel(
    const float* __restrict__ x, const int* __restrict__ ei,
    const float* __restrict__ edge_attr,
    const float* __restrict__ W1, const float* __restrict__ b1,
    const float* __restrict__ W2, const float* __restrict__ b2,
    float* __restrict__ out) {
  __shared__ float s_in[2][288];
  __shared__ float s_h[2][96];
  const int sub = threadIdx.x / 96;
  const int j = threadIdx.x - sub * 96;
  const int e = blockIdx.x * 2 + sub;

  const int s = ei[e];             // edge_index[0][e] = source
  const int d = ei[N_EDGES + e];   // edge_index[1][e] = destination
  s_in[sub][j] = x[(size_t)s * DIM + j];
  s_in[sub][96 + j] = x[(size_t)d * DIM + j];
  s_in[sub][192 + j] = edge_attr[(size_t)e * DIM + j];
  __syncthreads();

  float acc = b1[j];
  for (int k = 0; k < 288; k += 4) {
    const float4 iv = *reinterpret_cast<const float4*>(&s_in[sub][k]);
    acc = fmaf(iv.x, W1[(k + 0) * DIM + j], acc);
    acc = fmaf(iv.y, W1[(k + 1) * DIM + j], acc);
    acc = fmaf(iv.z, W1[(k + 2) * DIM + j], acc);
    acc = fmaf(iv.w, W1[(k + 3) * DIM + j], acc);
  }
  s_h[sub][j] = fmaxf(acc, 0.0f);
  __syncthreads();

  float acc2 = b2[j];
  for (int k = 0; k < 96; k += 4) {
    const float4 hv = *reinterpret_cast<const float4*>(&s_h[sub][k]);
    acc2 = fmaf(hv.x, W2[(k + 0) * DIM + j], acc2);
    acc2 = fmaf(hv.y, W2[(k + 1) * DIM + j], acc2);
    acc2 = fmaf(hv.z, W2[(k + 2) * DIM + j], acc2);
    acc2 = fmaf(hv.w, W2[(k + 3) * DIM + j], acc2);
  }
  out[(size_t)e * DIM + j] = acc2;
}

// ---------------------------------------------------------------------------
extern "C" void kernel_launch(void* const* d_in, const int* in_sizes, int n_in,
                              void* d_out, int out_size, void* d_ws,
                              size_t ws_size, hipStream_t stream) {
  const float* x = (const float*)d_in[0];
  const int* ei = (const int*)d_in[1];
  const float* edge_attr = (const float*)d_in[2];
  const float* Wn1 = (const float*)d_in[3];
  const float* bn1 = (const float*)d_in[4];
  const float* Wn2 = (const float*)d_in[5];
  const float* bn2 = (const float*)d_in[6];
  const float* We1 = (const float*)d_in[7];
  const float* be1 = (const float*)d_in[8];
  const float* We2 = (const float*)d_in[9];
  const float* be2 = (const float*)d_in[10];

  float* out = (float*)d_out;
  float* agg = (float*)d_ws;  // [N_NODES, DIM] fp32 scratch = 19.2 MB

  // Output layout: h_v [N*D] || edge_index [2*E] || h_e [E*D]
  float* out_hv = out;
  float* out_ei = out + (size_t)N_NODES * DIM;
  float* out_he = out + (size_t)N_NODES * DIM + 2 * (size_t)N_EDGES;

  // agg must be zeroed every call (ws is re-poisoned to 0xAA by the harness).
  hipMemsetAsync(d_ws, 0, (size_t)N_NODES * DIM * sizeof(float), stream);

  scatter_kernel<<<(N_EDGES * 24 + 255) / 256, 256, 0, stream>>>(edge_attr, ei,
                                                                 agg);
  copy_ei_kernel<<<(2 * N_EDGES + 255) / 256, 256, 0, stream>>>(ei, out_ei);
  node_mlp_kernel<<<N_NODES / 2, 192, 0, stream>>>(x, agg, Wn1, bn1, Wn2, bn2,
                                                   out_hv);
  edge_mlp_kernel<<<N_EDGES / 2, 192, 0, stream>>>(x, ei, edge_attr, We1, be1,
                                                   We2, be2, out_he);
}